// Round 14
// baseline (257.542 us; speedup 1.0000x reference)
//
#include <hip/hip_runtime.h>

typedef short short8 __attribute__((ext_vector_type(8)));
typedef float f32x4 __attribute__((ext_vector_type(4)));

union V16 { uint4 u; unsigned short s[8]; short8 v; };

#define CAP 48  // bucket capacity per node; Poisson(6) => P(deg>48) ~ 1e-30

__device__ __forceinline__ unsigned short f2bf(float f) {
  unsigned u = __builtin_bit_cast(unsigned, f);
  u += 0x7fffu + ((u >> 16) & 1u);
  return (unsigned short)(u >> 16);
}
__device__ __forceinline__ float bf2f(unsigned short b) {
  unsigned u = ((unsigned)b) << 16;
  return __builtin_bit_cast(float, u);
}
// packed f32x2 -> bf16x2 (RNE), single instruction
__device__ __forceinline__ unsigned cvtpk(float lo, float hi) {
  unsigned r;
  asm("v_cvt_pk_bf16_f32 %0, %1, %2" : "=v"(r) : "v"(lo), "v"(hi));
  return r;
}

// ---------------- weight frag transform: w[b][K][128] row-major ->
// frag f=(n0*KB+k0), lane l: 8 bf16 = w[k0*32+(l>>4)*8 + j][n0*16+(l&15)]
__device__ __forceinline__ void tcast_one(const float* __restrict__ w,
                                          uint4* __restrict__ wf, int K, int idx) {
  int NF64 = (K / 4) * 64;
  int b = idx / NF64;
  int r = idx - b * NF64;
  int f = r >> 6;
  int l = r & 63;
  int KB = K / 32;
  int n0 = f / KB;
  int k0 = f - n0 * KB;
  int n = n0 * 16 + (l & 15);
  int ks = k0 * 32 + (l >> 4) * 8;
  const float* src = w + (size_t)b * K * 128 + (size_t)ks * 128 + n;
  V16 o;
#pragma unroll
  for (int j = 0; j < 8; j++) o.s[j] = f2bf(src[j * 128]);
  wf[idx] = o.u;
}

// ---------------- prep: weight transforms + cursor zeroing + dtype detect
__global__ __launch_bounds__(512) void prep_kernel(
    const float* __restrict__ ie_w0, uint4* __restrict__ w0f_ie,
    const float* __restrict__ ie_w1, uint4* __restrict__ w1f_ie,
    const float* __restrict__ lw0, uint4* __restrict__ w0f_l,
    const float* __restrict__ lw1, uint4* __restrict__ w1f_l,
    uint4* __restrict__ cursor4, int nc4,
    const int* __restrict__ ei, int samples, int* __restrict__ flag) {
  int t = blockIdx.x * 512 + threadIdx.x;
  if (t < 1024) { tcast_one(ie_w0, w0f_ie, 64, t); return; }
  t -= 1024;
  if (t < 2048) { tcast_one(ie_w1, w1f_ie, 128, t); return; }
  t -= 2048;
  if (t < 6144) { tcast_one(lw0, w0f_l, 128, t); return; }
  t -= 6144;
  if (t < 6144) { tcast_one(lw1, w1f_l, 128, t); return; }
  t -= 6144;
  if (t < nc4) { uint4 z; z.x = 0; z.y = 0; z.z = 0; z.w = 0; cursor4[t] = z; return; }
  t -= nc4;
  if (t < samples && (t & 1) && ei[t] != 0) atomicOr(flag, 1);  // 1 => int32
}

// ---------------- bucket CSR fill, 1 edge/thread
__global__ void fill_kernel(const int* __restrict__ ei, const int* __restrict__ flag,
                            int* __restrict__ cursor, int* __restrict__ elist, int E) {
  int e = blockIdx.x * 256 + threadIdx.x;
  if (e >= E) return;
  int f = *flag;
  int s = f ? ei[e] : ei[(size_t)e * 2];
  int t = f ? ei[(size_t)E + e] : ei[((size_t)E + e) * 2];
  int p = atomicAdd(&cursor[t], 1);
  if (p < CAP) elist[t * CAP + p] = s;
}

// ---- shared MLP compute core: from afr fragments to z store (K=128 or 64) --
template <int K, bool OUTBF>
__device__ __forceinline__ void mlp_core(
    const short8 afr[K / 32], const uint4* wl, const float* bl,
    float* __restrict__ outF, unsigned short* __restrict__ outB,
    int r, int N, int lane) {
  constexpr int KB = K / 32;
  constexpr int NF0 = KB * 8;
  const int q = lane >> 4;
  const int c = lane & 15;
  const int sA = c + 32 * (q & 1);

  // GEMM1 (swapped): lane gets T[c][16*n0+4*q+j]
  f32x4 acc[8];
#pragma unroll
  for (int n0 = 0; n0 < 8; n0++) {
    acc[n0] = (f32x4){0.f, 0.f, 0.f, 0.f};
#pragma unroll
    for (int k0 = 0; k0 < KB; k0++) {
      V16 w; w.u = wl[(n0 * KB + k0) * 64 + lane];
      acc[n0] = __builtin_amdgcn_mfma_f32_16x16x32_bf16(w.v, afr[k0], acc[n0], 0, 0, 0);
    }
  }

  // bias + relu + pack pairs
  unsigned pk[8][2];
#pragma unroll
  for (int n0 = 0; n0 < 8; n0++) {
    f32x4 bb = *(const f32x4*)&bl[n0 * 16 + 4 * q];
    float t0 = acc[n0][0] + bb[0]; t0 = t0 > 0.f ? t0 : 0.f;
    float t1 = acc[n0][1] + bb[1]; t1 = t1 > 0.f ? t1 : 0.f;
    float t2 = acc[n0][2] + bb[2]; t2 = t2 > 0.f ? t2 : 0.f;
    float t3 = acc[n0][3] + bb[3]; t3 = t3 > 0.f ? t3 : 0.f;
    pk[n0][0] = cvtpk(t0, t1);
    pk[n0][1] = cvtpk(t2, t3);
  }

  // in-register transpose to GEMM2 B-fragments
  short8 b2[4];
#pragma unroll
  for (int k0 = 0; k0 < 4; k0++) {
    V16 t;
#pragma unroll
    for (int p = 0; p < 4; p++) {
      int src = sA + 16 * (p >> 1);
      unsigned lo = __shfl(pk[2 * k0][p & 1], src, 64);
      unsigned hi = __shfl(pk[2 * k0 + 1][p & 1], src, 64);
      (&t.u.x)[p] = (q & 2) ? hi : lo;
    }
    b2[k0] = t.v;
  }

  // GEMM2 (swapped): lane gets Z[c][16*n0+4*q+j]
  f32x4 z[8];
#pragma unroll
  for (int n0 = 0; n0 < 8; n0++) {
    z[n0] = (f32x4){0.f, 0.f, 0.f, 0.f};
#pragma unroll
    for (int k0 = 0; k0 < 4; k0++) {
      V16 w; w.u = wl[NF0 * 64 + (n0 * 4 + k0) * 64 + lane];
      z[n0] = __builtin_amdgcn_mfma_f32_16x16x32_bf16(w.v, b2[k0], z[n0], 0, 0, 0);
    }
  }

  // bias + SiLU + LayerNorm (2 shfl_xor) + packed store
  float sum = 0.f, sq = 0.f;
#pragma unroll
  for (int n0 = 0; n0 < 8; n0++) {
    f32x4 bb = *(const f32x4*)&bl[128 + n0 * 16 + 4 * q];
#pragma unroll
    for (int j = 0; j < 4; j++) {
      float v = z[n0][j] + bb[j];
      float sg = v / (1.f + __expf(-v));
      z[n0][j] = sg;
      sum += sg;
      sq += sg * sg;
    }
  }
  sum += __shfl_xor(sum, 16, 64);
  sum += __shfl_xor(sum, 32, 64);
  sq += __shfl_xor(sq, 16, 64);
  sq += __shfl_xor(sq, 32, 64);
  float mu = sum * (1.f / 128.f);
  float rs = rsqrtf(sq * (1.f / 128.f) - mu * mu + 1e-5f);

  if (r < N) {
#pragma unroll
    for (int n0 = 0; n0 < 8; n0++) {
      float v0 = (z[n0][0] - mu) * rs, v1 = (z[n0][1] - mu) * rs;
      float v2 = (z[n0][2] - mu) * rs, v3 = (z[n0][3] - mu) * rs;
      size_t o = (size_t)r * 128 + n0 * 16 + 4 * q;
      if (OUTBF) {
        uint2 st; st.x = cvtpk(v0, v1); st.y = cvtpk(v2, v3);
        *(uint2*)(outB + o) = st;
      } else {
        float4 st; st.x = v0; st.y = v1; st.z = v2; st.w = v3;
        *(float4*)(outF + o) = st;
      }
    }
  }
}

// ---- weight stage: direct global->LDS, linear layout (dest = base+lane*16) --
template <int TOT, int NF0>
__device__ __forceinline__ void stage_weights(const uint4* __restrict__ w0f,
                                              const uint4* __restrict__ w1f,
                                              uint4* wl, int tid, int wv) {
#pragma unroll
  for (int k = 0; k < TOT / 512; k++) {
    const int i = tid + k * 512;
    const uint4* src = (i < NF0 * 64) ? (w0f + i) : (w1f + (i - NF0 * 64));
    __builtin_amdgcn_global_load_lds(
        (const __attribute__((address_space(1))) void*)src,
        (__attribute__((address_space(3))) void*)(wl + (wv * 64 + k * 512)),
        16, 0, 0);
  }
}

// ================= standalone MLP (f32 in), as in R13 ========================
template <int K, bool OUTBF>
__device__ __forceinline__ void mlp_body(
    const float* __restrict__ in, const uint4* __restrict__ w0f,
    const float* __restrict__ b0, const uint4* __restrict__ w1f,
    const float* __restrict__ b1, float* __restrict__ outF,
    unsigned short* __restrict__ outB, int N, int ntiles,
    uint4* wl, float* bl, int tid) {
  constexpr int KB = K / 32;
  constexpr int NF0 = KB * 8;
  const int lane = tid & 63, wv = tid >> 6;
  stage_weights<(NF0 + 32) * 64, NF0>(w0f, w1f, wl, tid, wv);
  if (tid < 128) { bl[tid] = b0[tid]; bl[128 + tid] = b1[tid]; }
  __syncthreads();  // only barrier

  const int c = lane & 15;
  const int q = lane >> 4;

  for (int tile = blockIdx.x; tile < ntiles; tile += gridDim.x) {
    const int r = tile * 128 + wv * 16 + c;
    short8 afr[KB];
    if (r < N) {
      const float* rp = in + (size_t)r * K + q * 8;
#pragma unroll
      for (int k0 = 0; k0 < KB; k0++) {
        float4 a = *(const float4*)(rp + k0 * 32);
        float4 b = *(const float4*)(rp + k0 * 32 + 4);
        V16 o;
        o.u.x = cvtpk(a.x, a.y); o.u.y = cvtpk(a.z, a.w);
        o.u.z = cvtpk(b.x, b.y); o.u.w = cvtpk(b.z, b.w);
        afr[k0] = o.v;
      }
    } else {
#pragma unroll
      for (int k0 = 0; k0 < KB; k0++) {
        V16 o; o.u.x = 0; o.u.y = 0; o.u.z = 0; o.u.w = 0; afr[k0] = o.v;
      }
    }
    mlp_core<K, OUTBF>(afr, wl, bl, outF, outB, r, N, lane);
  }
}

__global__ __launch_bounds__(512, 4) void mlp64_kernel(
    const float* __restrict__ x, const uint4* __restrict__ w0f,
    const float* __restrict__ b0, const uint4* __restrict__ w1f,
    const float* __restrict__ b1, float* __restrict__ h0, int N, int ntiles) {
  __shared__ uint4 wl[48 * 64];
  __shared__ float bl[256];
  mlp_body<64, false>(x, w0f, b0, w1f, b1, h0, nullptr, N, ntiles,
                      wl, bl, threadIdx.x);
}

__global__ __launch_bounds__(512, 4) void mlp128_kernel(
    const float* __restrict__ in, const uint4* __restrict__ w0f,
    const float* __restrict__ b0, const uint4* __restrict__ w1f,
    const float* __restrict__ b1, unsigned short* __restrict__ outB,
    int N, int ntiles) {
  __shared__ uint4 wl[64 * 64];
  __shared__ float bl[256];
  mlp_body<128, true>(in, w0f, b0, w1f, b1, nullptr, outB, N, ntiles,
                      wl, bl, threadIdx.x);
}

// ================= FUSED gather+residual+MLP =================================
// lane (c,q) gathers cols q*8+32*k0 of row r -> accumulator lands exactly in
// the MLP A-fragment layout; h_new written once; MLP consumes registers.
__global__ __launch_bounds__(512) void gmlp_kernel(
    const unsigned short* __restrict__ zin, const int* __restrict__ elist,
    const int* __restrict__ cursor, float* __restrict__ h,
    const uint4* __restrict__ w0f, const float* __restrict__ b0,
    const uint4* __restrict__ w1f, const float* __restrict__ b1,
    unsigned short* __restrict__ zout, int N, int ntiles) {
  __shared__ uint4 wl[64 * 64];
  __shared__ float bl[256];
  const int tid = threadIdx.x, lane = tid & 63, wv = tid >> 6;
  stage_weights<64 * 64, 32>(w0f, w1f, wl, tid, wv);
  if (tid < 128) { bl[tid] = b0[tid]; bl[128 + tid] = b1[tid]; }
  __syncthreads();  // only barrier

  const int c = lane & 15;
  const int q = lane >> 4;

  for (int tile = blockIdx.x; tile < ntiles; tile += gridDim.x) {
    const int r = tile * 128 + wv * 16 + c;
    float hv[4][8];
    if (r < N) {
      // h_old (issued first; in flight under the gather loop)
      const float* hp = h + (size_t)r * 128 + q * 8;
      float4 ha[4], hb[4];
#pragma unroll
      for (int k0 = 0; k0 < 4; k0++) {
        ha[k0] = *(const float4*)(hp + k0 * 32);
        hb[k0] = *(const float4*)(hp + k0 * 32 + 4);
      }
      int n = cursor[r];
      n = n < CAP ? n : CAP;
      const int o = r * CAP;
      float acc[4][8];
#pragma unroll
      for (int k0 = 0; k0 < 4; k0++)
#pragma unroll
        for (int j = 0; j < 8; j++) acc[k0][j] = 0.f;
      const unsigned short* zq = zin + q * 8;
      int i = 0;
      for (; i + 2 <= n; i += 2) {
        int s0 = elist[o + i], s1 = elist[o + i + 1];
        V16 u0[4], u1[4];
#pragma unroll
        for (int k0 = 0; k0 < 4; k0++) {
          u0[k0].u = *(const uint4*)(zq + (size_t)s0 * 128 + k0 * 32);
          u1[k0].u = *(const uint4*)(zq + (size_t)s1 * 128 + k0 * 32);
        }
#pragma unroll
        for (int k0 = 0; k0 < 4; k0++)
#pragma unroll
          for (int j = 0; j < 8; j++)
            acc[k0][j] += bf2f(u0[k0].s[j]) + bf2f(u1[k0].s[j]);
      }
      if (i < n) {
        int s0 = elist[o + i];
        V16 u0[4];
#pragma unroll
        for (int k0 = 0; k0 < 4; k0++)
          u0[k0].u = *(const uint4*)(zq + (size_t)s0 * 128 + k0 * 32);
#pragma unroll
        for (int k0 = 0; k0 < 4; k0++)
#pragma unroll
          for (int j = 0; j < 8; j++) acc[k0][j] += bf2f(u0[k0].s[j]);
      }
      float inv = n > 0 ? 1.f / (float)n : 0.f;
      float* hw = h + (size_t)r * 128 + q * 8;
#pragma unroll
      for (int k0 = 0; k0 < 4; k0++) {
        hv[k0][0] = ha[k0].x + acc[k0][0] * inv;
        hv[k0][1] = ha[k0].y + acc[k0][1] * inv;
        hv[k0][2] = ha[k0].z + acc[k0][2] * inv;
        hv[k0][3] = ha[k0].w + acc[k0][3] * inv;
        hv[k0][4] = hb[k0].x + acc[k0][4] * inv;
        hv[k0][5] = hb[k0].y + acc[k0][5] * inv;
        hv[k0][6] = hb[k0].z + acc[k0][6] * inv;
        hv[k0][7] = hb[k0].w + acc[k0][7] * inv;
        float4 s0, s1;
        s0.x = hv[k0][0]; s0.y = hv[k0][1]; s0.z = hv[k0][2]; s0.w = hv[k0][3];
        s1.x = hv[k0][4]; s1.y = hv[k0][5]; s1.z = hv[k0][6]; s1.w = hv[k0][7];
        *(float4*)(hw + k0 * 32) = s0;
        *(float4*)(hw + k0 * 32 + 4) = s1;
      }
    } else {
#pragma unroll
      for (int k0 = 0; k0 < 4; k0++)
#pragma unroll
        for (int j = 0; j < 8; j++) hv[k0][j] = 0.f;
    }

    // pack h_new -> A-fragments and run the MLP
    short8 afr[4];
#pragma unroll
    for (int k0 = 0; k0 < 4; k0++) {
      V16 o;
      o.u.x = cvtpk(hv[k0][0], hv[k0][1]);
      o.u.y = cvtpk(hv[k0][2], hv[k0][3]);
      o.u.z = cvtpk(hv[k0][4], hv[k0][5]);
      o.u.w = cvtpk(hv[k0][6], hv[k0][7]);
      afr[k0] = o.v;
    }
    mlp_core<128, true>(afr, wl, bl, nullptr, zout, r, N, lane);
  }
}

// ---------------- standalone gather + residual (final layer -> f32 d_out)
__global__ __launch_bounds__(256) void gather_kernel(
    const unsigned short* __restrict__ z, const int* __restrict__ elist,
    const int* __restrict__ cursor, float* __restrict__ h, int N) {
  int t = blockIdx.x * 256 + threadIdx.x;
  int g = t >> 4;
  if (g >= N) return;
  int lane = threadIdx.x & 63;
  int gb = lane & 48;
  int sub = lane & 15;
  int c = sub * 8;
  int o = g * CAP;
  int n = cursor[g];
  n = n < CAP ? n : CAP;
  float* hp = h + (size_t)g * 128 + c;
  float4 h0 = *(const float4*)hp, h1 = *(const float4*)(hp + 4);
  float acc[8] = {0.f, 0.f, 0.f, 0.f, 0.f, 0.f, 0.f, 0.f};
  for (int base = 0; base < n; base += 16) {
    int m = n - base;
    m = m < 16 ? m : 16;
    int sidx = (sub < m) ? elist[o + base + sub] : 0;
    int i = 0;
    for (; i + 4 <= m; i += 4) {
      int s0 = __shfl(sidx, gb + i, 64);
      int s1 = __shfl(sidx, gb + i + 1, 64);
      int s2 = __shfl(sidx, gb + i + 2, 64);
      int s3 = __shfl(sidx, gb + i + 3, 64);
      V16 v0, v1, v2, v3;
      v0.u = *(const uint4*)(z + (size_t)s0 * 128 + c);
      v1.u = *(const uint4*)(z + (size_t)s1 * 128 + c);
      v2.u = *(const uint4*)(z + (size_t)s2 * 128 + c);
      v3.u = *(const uint4*)(z + (size_t)s3 * 128 + c);
#pragma unroll
      for (int j = 0; j < 8; j++)
        acc[j] += (bf2f(v0.s[j]) + bf2f(v1.s[j])) + (bf2f(v2.s[j]) + bf2f(v3.s[j]));
    }
    for (; i < m; i++) {
      int s0 = __shfl(sidx, gb + i, 64);
      V16 v0;
      v0.u = *(const uint4*)(z + (size_t)s0 * 128 + c);
#pragma unroll
      for (int j = 0; j < 8; j++) acc[j] += bf2f(v0.s[j]);
    }
  }
  float inv = n > 0 ? 1.f / (float)n : 0.f;
  h0.x += acc[0] * inv; h0.y += acc[1] * inv; h0.z += acc[2] * inv; h0.w += acc[3] * inv;
  h1.x += acc[4] * inv; h1.y += acc[5] * inv; h1.z += acc[6] * inv; h1.w += acc[7] * inv;
  *(float4*)hp = h0;
  *(float4*)(hp + 4) = h1;
}

extern "C" void kernel_launch(void* const* d_in, const int* in_sizes, int n_in,
                              void* d_out, int out_size, void* d_ws, size_t ws_size,
                              hipStream_t stream) {
  const float* x = (const float*)d_in[0];
  const int* ei = (const int*)d_in[1];
  const float* ie_w0 = (const float*)d_in[2];
  const float* ie_b0 = (const float*)d_in[3];
  const float* ie_w1 = (const float*)d_in[4];
  const float* ie_b1 = (const float*)d_in[5];
  const float* lw0 = (const float*)d_in[6];
  const float* lb0 = (const float*)d_in[7];
  const float* lw1 = (const float*)d_in[8];
  const float* lb1 = (const float*)d_in[9];
  const int N = in_sizes[0] / 64;
  const int E = in_sizes[1] / 2;
  float* h = (float*)d_out;

  char* ws = (char*)d_ws;
  size_t off_b = 0;
  auto carve = [&](size_t bytes) { void* p = ws + off_b; off_b = (off_b + bytes + 255) & ~(size_t)255; return p; };
  unsigned short* zbufA = (unsigned short*)carve((size_t)N * 128 * 2);
  unsigned short* zbufB = (unsigned short*)carve((size_t)N * 128 * 2);
  int* elist = (int*)carve((size_t)N * CAP * 4);
  int* flag = (int*)carve(256);
  int* cursor = (int*)carve((size_t)N * 4 + 16);
  uint4* w0f_ie = (uint4*)carve(16 * 64 * 16);
  uint4* w1f_ie = (uint4*)carve(32 * 64 * 16);
  uint4* w0f_l = (uint4*)carve(3 * 32 * 64 * 16);
  uint4* w1f_l = (uint4*)carve(3 * 32 * 64 * 16);

  const int ntiles = (N + 127) / 128;
  const int mgrid = ntiles < 512 ? ntiles : 512;
  const int nc4 = (N + 3) / 4;
  int samples = 2 * E < 8192 ? 2 * E : 8192;

  hipMemsetAsync(flag, 0, 4, stream);
  prep_kernel<<<(15360 + nc4 + samples + 511) / 512, 512, 0, stream>>>(
      ie_w0, w0f_ie, ie_w1, w1f_ie, lw0, w0f_l, lw1, w1f_l,
      (uint4*)cursor, nc4, ei, samples, flag);

  fill_kernel<<<(E + 255) / 256, 256, 0, stream>>>(ei, flag, cursor, elist, E);

  // h0 = MLP_ie(x)
  mlp64_kernel<<<mgrid, 512, 0, stream>>>(
      x, w0f_ie, ie_b0, w1f_ie, ie_b1, h, N, ntiles);

  // z0 = MLP_0(h0)
  mlp128_kernel<<<mgrid, 512, 0, stream>>>(
      h, w0f_l, lb0, w1f_l, lb1, zbufA, N, ntiles);

  // fused: h1 = h0 + agg(z0); z1 = MLP_1(h1)
  gmlp_kernel<<<mgrid, 512, 0, stream>>>(
      zbufA, elist, cursor, h,
      w0f_l + (size_t)1 * 32 * 64, lb0 + 128,
      w1f_l + (size_t)1 * 32 * 64, lb1 + 128, zbufB, N, ntiles);

  // fused: h2 = h1 + agg(z1); z2 = MLP_2(h2)
  gmlp_kernel<<<mgrid, 512, 0, stream>>>(
      zbufB, elist, cursor, h,
      w0f_l + (size_t)2 * 32 * 64, lb0 + 256,
      w1f_l + (size_t)2 * 32 * 64, lb1 + 256, zbufA, N, ntiles);

  // final: h3 = h2 + agg(z2)  (f32 d_out)
  gather_kernel<<<((size_t)N * 16 + 255) / 256, 256, 0, stream>>>(
      zbufA, elist, cursor, h, N);
}

// Round 15
// 245.872 us; speedup vs baseline: 1.0475x; 1.0475x over previous
//
#include <hip/hip_runtime.h>

typedef short short8 __attribute__((ext_vector_type(8)));
typedef float f32x4 __attribute__((ext_vector_type(4)));

union V16 { uint4 u; unsigned short s[8]; short8 v; };

#define CAP 48  // bucket capacity per node; Poisson(6) => P(deg>48) ~ 1e-30

__device__ __forceinline__ unsigned short f2bf(float f) {
  unsigned u = __builtin_bit_cast(unsigned, f);
  u += 0x7fffu + ((u >> 16) & 1u);
  return (unsigned short)(u >> 16);
}
__device__ __forceinline__ float bf2f(unsigned short b) {
  unsigned u = ((unsigned)b) << 16;
  return __builtin_bit_cast(float, u);
}
// packed f32x2 -> bf16x2 (RNE), single instruction
__device__ __forceinline__ unsigned cvtpk(float lo, float hi) {
  unsigned r;
  asm("v_cvt_pk_bf16_f32 %0, %1, %2" : "=v"(r) : "v"(lo), "v"(hi));
  return r;
}

// ---------------- weight frag transform: w[b][K][128] row-major ->
// frag f=(n0*KB+k0), lane l: 8 bf16 = w[k0*32+(l>>4)*8 + j][n0*16+(l&15)]
__device__ __forceinline__ void tcast_one(const float* __restrict__ w,
                                          uint4* __restrict__ wf, int K, int idx) {
  int NF64 = (K / 4) * 64;
  int b = idx / NF64;
  int r = idx - b * NF64;
  int f = r >> 6;
  int l = r & 63;
  int KB = K / 32;
  int n0 = f / KB;
  int k0 = f - n0 * KB;
  int n = n0 * 16 + (l & 15);
  int ks = k0 * 32 + (l >> 4) * 8;
  const float* src = w + (size_t)b * K * 128 + (size_t)ks * 128 + n;
  V16 o;
#pragma unroll
  for (int j = 0; j < 8; j++) o.s[j] = f2bf(src[j * 128]);
  wf[idx] = o.u;
}

// ---------------- prep: weight transforms + cursor zeroing + dtype detect
__global__ __launch_bounds__(512) void prep_kernel(
    const float* __restrict__ ie_w0, uint4* __restrict__ w0f_ie,
    const float* __restrict__ ie_w1, uint4* __restrict__ w1f_ie,
    const float* __restrict__ lw0, uint4* __restrict__ w0f_l,
    const float* __restrict__ lw1, uint4* __restrict__ w1f_l,
    uint4* __restrict__ cursor4, int nc4,
    const int* __restrict__ ei, int samples, int* __restrict__ flag) {
  int t = blockIdx.x * 512 + threadIdx.x;
  if (t < 1024) { tcast_one(ie_w0, w0f_ie, 64, t); return; }
  t -= 1024;
  if (t < 2048) { tcast_one(ie_w1, w1f_ie, 128, t); return; }
  t -= 2048;
  if (t < 6144) { tcast_one(lw0, w0f_l, 128, t); return; }
  t -= 6144;
  if (t < 6144) { tcast_one(lw1, w1f_l, 128, t); return; }
  t -= 6144;
  if (t < nc4) { uint4 z; z.x = 0; z.y = 0; z.z = 0; z.w = 0; cursor4[t] = z; return; }
  t -= nc4;
  if (t < samples && (t & 1) && ei[t] != 0) atomicOr(flag, 1);  // 1 => int32
}

// ---------------- bucket CSR fill, 1 edge/thread
__global__ void fill_kernel(const int* __restrict__ ei, const int* __restrict__ flag,
                            int* __restrict__ cursor, int* __restrict__ elist, int E) {
  int e = blockIdx.x * 256 + threadIdx.x;
  if (e >= E) return;
  int f = *flag;
  int s = f ? ei[e] : ei[(size_t)e * 2];
  int t = f ? ei[(size_t)E + e] : ei[((size_t)E + e) * 2];
  int p = atomicAdd(&cursor[t], 1);
  if (p < CAP) elist[t * CAP + p] = s;
}

// ---- pk pairs -> B-fragments via in-register transpose (shared helper) -----
__device__ __forceinline__ void make_bfrags(const unsigned pk[8][2], int lane,
                                            short8 b2[4]) {
  const int q = lane >> 4;
  const int c = lane & 15;
  const int sA = c + 32 * (q & 1);
#pragma unroll
  for (int k0 = 0; k0 < 4; k0++) {
    V16 t;
#pragma unroll
    for (int p = 0; p < 4; p++) {
      int src = sA + 16 * (p >> 1);
      unsigned lo = __shfl(pk[2 * k0][p & 1], src, 64);
      unsigned hi = __shfl(pk[2 * k0 + 1][p & 1], src, 64);
      (&t.u.x)[p] = (q & 2) ? hi : lo;
    }
    b2[k0] = t.v;
  }
}

// ---- MLP compute: afr fragments -> post-LN normalized values (registers) ---
// bl: b0 at [0..127], b1 at [128..255]
template <int K>
__device__ __forceinline__ void mlp_compute(
    const short8* afr, const uint4* wl, const float* bl, int lane, f32x4 z[8]) {
  constexpr int KB = K / 32;
  constexpr int NF0 = KB * 8;
  const int q = lane >> 4;

  // GEMM1 (swapped): lane gets T[c][16*n0+4*q+j]
  f32x4 acc[8];
#pragma unroll
  for (int n0 = 0; n0 < 8; n0++) {
    acc[n0] = (f32x4){0.f, 0.f, 0.f, 0.f};
#pragma unroll
    for (int k0 = 0; k0 < KB; k0++) {
      V16 w; w.u = wl[(n0 * KB + k0) * 64 + lane];
      acc[n0] = __builtin_amdgcn_mfma_f32_16x16x32_bf16(w.v, afr[k0], acc[n0], 0, 0, 0);
    }
  }

  // bias + relu + pack pairs
  unsigned pk[8][2];
#pragma unroll
  for (int n0 = 0; n0 < 8; n0++) {
    f32x4 bb = *(const f32x4*)&bl[n0 * 16 + 4 * q];
    float t0 = acc[n0][0] + bb[0]; t0 = t0 > 0.f ? t0 : 0.f;
    float t1 = acc[n0][1] + bb[1]; t1 = t1 > 0.f ? t1 : 0.f;
    float t2 = acc[n0][2] + bb[2]; t2 = t2 > 0.f ? t2 : 0.f;
    float t3 = acc[n0][3] + bb[3]; t3 = t3 > 0.f ? t3 : 0.f;
    pk[n0][0] = cvtpk(t0, t1);
    pk[n0][1] = cvtpk(t2, t3);
  }

  short8 b2[4];
  make_bfrags(pk, lane, b2);

  // GEMM2 (swapped): lane gets Z[c][16*n0+4*q+j]
#pragma unroll
  for (int n0 = 0; n0 < 8; n0++) {
    z[n0] = (f32x4){0.f, 0.f, 0.f, 0.f};
#pragma unroll
    for (int k0 = 0; k0 < 4; k0++) {
      V16 w; w.u = wl[NF0 * 64 + (n0 * 4 + k0) * 64 + lane];
      z[n0] = __builtin_amdgcn_mfma_f32_16x16x32_bf16(w.v, b2[k0], z[n0], 0, 0, 0);
    }
  }

  // bias + SiLU + LayerNorm (2 shfl_xor); normalize in place
  float sum = 0.f, sq = 0.f;
#pragma unroll
  for (int n0 = 0; n0 < 8; n0++) {
    f32x4 bb = *(const f32x4*)&bl[128 + n0 * 16 + 4 * q];
#pragma unroll
    for (int j = 0; j < 4; j++) {
      float v = z[n0][j] + bb[j];
      float sg = v / (1.f + __expf(-v));
      z[n0][j] = sg;
      sum += sg;
      sq += sg * sg;
    }
  }
  sum += __shfl_xor(sum, 16, 64);
  sum += __shfl_xor(sum, 32, 64);
  sq += __shfl_xor(sq, 16, 64);
  sq += __shfl_xor(sq, 32, 64);
  float mu = sum * (1.f / 128.f);
  float rs = rsqrtf(sq * (1.f / 128.f) - mu * mu + 1e-5f);
#pragma unroll
  for (int n0 = 0; n0 < 8; n0++)
#pragma unroll
    for (int j = 0; j < 4; j++) z[n0][j] = (z[n0][j] - mu) * rs;
}

// ---- weight stage: direct global->LDS, linear layout ------------------------
template <int TOT, int NF0>
__device__ __forceinline__ void stage_weights(const uint4* __restrict__ w0f,
                                              const uint4* __restrict__ w1f,
                                              uint4* wl, int tid, int wv) {
#pragma unroll
  for (int k = 0; k < TOT / 512; k++) {
    const int i = tid + k * 512;
    const uint4* src = (i < NF0 * 64) ? (w0f + i) : (w1f + (i - NF0 * 64));
    __builtin_amdgcn_global_load_lds(
        (const __attribute__((address_space(1))) void*)src,
        (__attribute__((address_space(3))) void*)(wl + (wv * 64 + k * 512)),
        16, 0, 0);
  }
}

// ---- load one f32 input row -> bf16 A-fragments -----------------------------
template <int K>
__device__ __forceinline__ void load_afr(const float* __restrict__ in, int r, int N,
                                         int lane, short8* afr) {
  constexpr int KB = K / 32;
  const int q = lane >> 4;
  if (r < N) {
    const float* rp = in + (size_t)r * K + q * 8;
#pragma unroll
    for (int k0 = 0; k0 < KB; k0++) {
      float4 a = *(const float4*)(rp + k0 * 32);
      float4 b = *(const float4*)(rp + k0 * 32 + 4);
      V16 o;
      o.u.x = cvtpk(a.x, a.y); o.u.y = cvtpk(a.z, a.w);
      o.u.z = cvtpk(b.x, b.y); o.u.w = cvtpk(b.z, b.w);
      afr[k0] = o.v;
    }
  } else {
#pragma unroll
    for (int k0 = 0; k0 < KB; k0++) {
      V16 o; o.u.x = 0; o.u.y = 0; o.u.z = 0; o.u.w = 0; afr[k0] = o.v;
    }
  }
}

// ================= standalone layer MLP (K=128, f32 in, bf16 out) ===========
__global__ __launch_bounds__(512, 4) void mlp128_kernel(
    const float* __restrict__ in, const uint4* __restrict__ w0f,
    const float* __restrict__ b0, const uint4* __restrict__ w1f,
    const float* __restrict__ b1, unsigned short* __restrict__ outB,
    int N, int ntiles) {
  __shared__ uint4 wl[64 * 64];
  __shared__ float bl[256];
  const int tid = threadIdx.x, lane = tid & 63, wv = tid >> 6;
  stage_weights<64 * 64, 32>(w0f, w1f, wl, tid, wv);
  if (tid < 128) { bl[tid] = b0[tid]; bl[128 + tid] = b1[tid]; }
  __syncthreads();

  const int c = lane & 15;
  const int q = lane >> 4;
  for (int tile = blockIdx.x; tile < ntiles; tile += gridDim.x) {
    const int r = tile * 128 + wv * 16 + c;
    short8 afr[4];
    load_afr<128>(in, r, N, lane, afr);
    f32x4 z[8];
    mlp_compute<128>(afr, wl, bl, lane, z);
    if (r < N) {
#pragma unroll
      for (int n0 = 0; n0 < 8; n0++) {
        uint2 st;
        st.x = cvtpk(z[n0][0], z[n0][1]);
        st.y = cvtpk(z[n0][2], z[n0][3]);
        *(uint2*)(outB + (size_t)r * 128 + n0 * 16 + 4 * q) = st;
      }
    }
  }
}

// ================= FUSED MLP_ie + MLP_layer0 =================================
// Phase A (ie weights, K=64): x -> h0; write h0 f32; keep layer-0 B-fragments
// in registers (same cvtpk+shfl transpose as intra-MLP). Restage weights.
// Phase B (layer-0 weights, K=128): fragments -> z0 (bf16).
// Grid sized so each block owns at most 2 tiles.
__global__ __launch_bounds__(512) void mlp2_kernel(
    const float* __restrict__ x,
    const uint4* __restrict__ w0f_ie, const float* __restrict__ b0i,
    const uint4* __restrict__ w1f_ie, const float* __restrict__ b1i,
    const uint4* __restrict__ w0f_l, const float* __restrict__ b0l,
    const uint4* __restrict__ w1f_l, const float* __restrict__ b1l,
    float* __restrict__ h0, unsigned short* __restrict__ z0,
    int N, int ntiles) {
  __shared__ uint4 wl[64 * 64];
  __shared__ float bl[512];   // [0]ie_b0 [128]ie_b1 [256]l_b0 [384]l_b1
  const int tid = threadIdx.x, lane = tid & 63, wv = tid >> 6;
  stage_weights<48 * 64, 16>(w0f_ie, w1f_ie, wl, tid, wv);
  if (tid < 128) {
    bl[tid] = b0i[tid]; bl[128 + tid] = b1i[tid];
    bl[256 + tid] = b0l[tid]; bl[384 + tid] = b1l[tid];
  }
  __syncthreads();

  const int c = lane & 15;
  const int q = lane >> 4;

  short8 fsave[2][4];  // layer-0 B-fragments per owned tile

  // ---- phase A: initial embedding
#pragma unroll
  for (int t = 0; t < 2; t++) {
    const int tile = blockIdx.x + t * gridDim.x;
    if (tile >= ntiles) break;
    const int r = tile * 128 + wv * 16 + c;
    short8 afr[2];
    load_afr<64>(x, r, N, lane, afr);
    f32x4 z[8];
    mlp_compute<64>(afr, wl, bl, lane, z);
    if (r < N) {
      float* hw = h0 + (size_t)r * 128 + q * 4;  // cols n0*16+4q
#pragma unroll
      for (int n0 = 0; n0 < 8; n0++) {
        float4 st; st.x = z[n0][0]; st.y = z[n0][1]; st.z = z[n0][2]; st.w = z[n0][3];
        *(float4*)(hw + n0 * 16) = st;
      }
    }
    // h0 row -> layer-0 B-fragments (same transpose as intra-MLP)
    unsigned pk[8][2];
#pragma unroll
    for (int n0 = 0; n0 < 8; n0++) {
      pk[n0][0] = cvtpk(z[n0][0], z[n0][1]);
      pk[n0][1] = cvtpk(z[n0][2], z[n0][3]);
    }
    make_bfrags(pk, lane, fsave[t]);
  }
  __syncthreads();  // all reads of ie weights done

  // ---- restage: layer-0 weights
  stage_weights<64 * 64, 32>(w0f_l, w1f_l, wl, tid, wv);
  __syncthreads();

  // ---- phase B: layer-0 MLP from registers
#pragma unroll
  for (int t = 0; t < 2; t++) {
    const int tile = blockIdx.x + t * gridDim.x;
    if (tile >= ntiles) break;
    const int r = tile * 128 + wv * 16 + c;
    f32x4 z[8];
    mlp_compute<128>(fsave[t], wl, bl + 256, lane, z);
    if (r < N) {
#pragma unroll
      for (int n0 = 0; n0 < 8; n0++) {
        uint2 st;
        st.x = cvtpk(z[n0][0], z[n0][1]);
        st.y = cvtpk(z[n0][2], z[n0][3]);
        *(uint2*)(z0 + (size_t)r * 128 + n0 * 16 + 4 * q) = st;
      }
    }
  }
}

// ---------------- gather + residual: h[n] += mean_{e in bucket[n]} z[src[e]]
__global__ __launch_bounds__(256) void gather_kernel(
    const unsigned short* __restrict__ z, const int* __restrict__ elist,
    const int* __restrict__ cursor, float* __restrict__ h, int N) {
  int t = blockIdx.x * 256 + threadIdx.x;
  int g = t >> 4;
  if (g >= N) return;
  int lane = threadIdx.x & 63;
  int gb = lane & 48;
  int sub = lane & 15;
  int c = sub * 8;
  int o = g * CAP;
  int n = cursor[g];
  n = n < CAP ? n : CAP;
  float* hp = h + (size_t)g * 128 + c;
  float4 h0 = *(const float4*)hp, h1 = *(const float4*)(hp + 4);
  float acc[8] = {0.f, 0.f, 0.f, 0.f, 0.f, 0.f, 0.f, 0.f};
  for (int base = 0; base < n; base += 16) {
    int m = n - base;
    m = m < 16 ? m : 16;
    int sidx = (sub < m) ? elist[o + base + sub] : 0;
    int i = 0;
    for (; i + 4 <= m; i += 4) {
      int s0 = __shfl(sidx, gb + i, 64);
      int s1 = __shfl(sidx, gb + i + 1, 64);
      int s2 = __shfl(sidx, gb + i + 2, 64);
      int s3 = __shfl(sidx, gb + i + 3, 64);
      V16 v0, v1, v2, v3;
      v0.u = *(const uint4*)(z + (size_t)s0 * 128 + c);
      v1.u = *(const uint4*)(z + (size_t)s1 * 128 + c);
      v2.u = *(const uint4*)(z + (size_t)s2 * 128 + c);
      v3.u = *(const uint4*)(z + (size_t)s3 * 128 + c);
#pragma unroll
      for (int j = 0; j < 8; j++)
        acc[j] += (bf2f(v0.s[j]) + bf2f(v1.s[j])) + (bf2f(v2.s[j]) + bf2f(v3.s[j]));
    }
    for (; i < m; i++) {
      int s0 = __shfl(sidx, gb + i, 64);
      V16 v0;
      v0.u = *(const uint4*)(z + (size_t)s0 * 128 + c);
#pragma unroll
      for (int j = 0; j < 8; j++) acc[j] += bf2f(v0.s[j]);
    }
  }
  float inv = n > 0 ? 1.f / (float)n : 0.f;
  h0.x += acc[0] * inv; h0.y += acc[1] * inv; h0.z += acc[2] * inv; h0.w += acc[3] * inv;
  h1.x += acc[4] * inv; h1.y += acc[5] * inv; h1.z += acc[6] * inv; h1.w += acc[7] * inv;
  *(float4*)hp = h0;
  *(float4*)(hp + 4) = h1;
}

extern "C" void kernel_launch(void* const* d_in, const int* in_sizes, int n_in,
                              void* d_out, int out_size, void* d_ws, size_t ws_size,
                              hipStream_t stream) {
  const float* x = (const float*)d_in[0];
  const int* ei = (const int*)d_in[1];
  const float* ie_w0 = (const float*)d_in[2];
  const float* ie_b0 = (const float*)d_in[3];
  const float* ie_w1 = (const float*)d_in[4];
  const float* ie_b1 = (const float*)d_in[5];
  const float* lw0 = (const float*)d_in[6];
  const float* lb0 = (const float*)d_in[7];
  const float* lw1 = (const float*)d_in[8];
  const float* lb1 = (const float*)d_in[9];
  const int N = in_sizes[0] / 64;
  const int E = in_sizes[1] / 2;
  float* h = (float*)d_out;

  char* ws = (char*)d_ws;
  size_t off_b = 0;
  auto carve = [&](size_t bytes) { void* p = ws + off_b; off_b = (off_b + bytes + 255) & ~(size_t)255; return p; };
  unsigned short* zbuf = (unsigned short*)carve((size_t)N * 128 * 2);
  int* elist = (int*)carve((size_t)N * CAP * 4);
  int* flag = (int*)carve(256);
  int* cursor = (int*)carve((size_t)N * 4 + 16);
  uint4* w0f_ie = (uint4*)carve(16 * 64 * 16);
  uint4* w1f_ie = (uint4*)carve(32 * 64 * 16);
  uint4* w0f_l = (uint4*)carve(3 * 32 * 64 * 16);
  uint4* w1f_l = (uint4*)carve(3 * 32 * 64 * 16);

  const int ntiles = (N + 127) / 128;
  const int mgrid = ntiles < 512 ? ntiles : 512;
  const int mgrid2 = (ntiles + 1) / 2;   // fused kernel: <=2 tiles/block
  const int nc4 = (N + 3) / 4;
  int samples = 2 * E < 8192 ? 2 * E : 8192;

  hipMemsetAsync(flag, 0, 4, stream);
  prep_kernel<<<(15360 + nc4 + samples + 511) / 512, 512, 0, stream>>>(
      ie_w0, w0f_ie, ie_w1, w1f_ie, lw0, w0f_l, lw1, w1f_l,
      (uint4*)cursor, nc4, ei, samples, flag);

  fill_kernel<<<(E + 255) / 256, 256, 0, stream>>>(ei, flag, cursor, elist, E);

  // fused: h0 = MLP_ie(x) (f32 out); z0 = MLP_0(h0) (bf16 out)
  mlp2_kernel<<<mgrid2, 512, 0, stream>>>(
      x, w0f_ie, ie_b0, w1f_ie, ie_b1,
      w0f_l, lb0, w1f_l, lb1, h, zbuf, N, ntiles);
  gather_kernel<<<((size_t)N * 16 + 255) / 256, 256, 0, stream>>>(
      zbuf, elist, cursor, h, N);

  for (int l = 1; l < 3; l++) {
    mlp128_kernel<<<mgrid, 512, 0, stream>>>(
        h, w0f_l + (size_t)l * 32 * 64, lb0 + (size_t)l * 128,
        w1f_l + (size_t)l * 32 * 64, lb1 + (size_t)l * 128, zbuf, N, ntiles);
    gather_kernel<<<((size_t)N * 16 + 255) / 256, 256, 0, stream>>>(
        zbuf, elist, cursor, h, N);
  }
}